// Round 2
// baseline (332.649 us; speedup 1.0000x reference)
//
#include <hip/hip_runtime.h>

// Weighted order statistic, B=4,C=3,K=3,NC=16,H=W=128, D=27, MD=54.
// One thread per (pixel, nc). A_d = w_d + sum_e w_e * [v_e > v_d] computed
// pairwise (no sort); answer = v at argmax{A_d : A_d <= bias}, fallback max v.
// Weights accumulated in f64 so the A<=t decision matches an exact reference.
// NOTE output layout: reference does y.reshape(b,NC,h,w) on a (b*hw, NC)
// buffer WITHOUT transpose -> flat order is (b, hw, nc).

#define NCH 16
#define DD  27
#define MDD 54
#define WPAD 55
#define HH  128
#define WW  128
#define CCH 3

__global__ __launch_bounds__(256) void wos_kernel(
    const float* __restrict__ xin,
    const float* __restrict__ mask,
    const float* __restrict__ weight,
    const float* __restrict__ bias,
    float* __restrict__ out)
{
  __shared__ float  mL[NCH * DD];      // mask rows (f32)
  __shared__ double wL[NCH * WPAD];    // weights widened to f64 (padded stride)
  __shared__ float  bL[NCH];           // bias
  __shared__ float  pL[DD][16];        // per-pixel patch, for dynamic e-indexing

  const int tid = threadIdx.x;
  for (int i = tid; i < NCH * DD; i += 256) mL[i] = mask[i];
  for (int i = tid; i < NCH * MDD; i += 256)
    wL[(i / MDD) * WPAD + (i % MDD)] = (double)weight[i];
  if (tid < NCH) bL[tid] = bias[tid];

  const int nc  = tid & 15;
  const int pix = tid >> 4;
  const int n   = (int)blockIdx.x * 16 + pix;   // grid covers B*H*W = 65536 exactly
  const int b   = n >> 14;                      // H*W = 16384
  const int rem = n & 16383;
  const int py  = rem >> 7;
  const int px  = rem & 127;

  // load 3x3x3 patch with 'same' zero padding (d = c*9 + i*3 + j)
  float p[DD];
  #pragma unroll
  for (int c = 0; c < CCH; ++c) {
    #pragma unroll
    for (int i = 0; i < 3; ++i) {
      const int ys = py + i - 1;
      const bool yok = (ys >= 0) && (ys < HH);
      #pragma unroll
      for (int j = 0; j < 3; ++j) {
        const int xs = px + j - 1;
        const bool ok = yok && (xs >= 0) && (xs < WW);
        const int idx = ((b * CCH + c) * HH + (ok ? ys : 0)) * WW + (ok ? xs : 0);
        p[c * 9 + i * 3 + j] = ok ? xin[idx] : 0.0f;
      }
    }
  }

  // all 16 nc-threads of a pixel computed identical p; nc==0 publishes it
  if (nc == 0) {
    #pragma unroll
    for (int d = 0; d < DD; ++d) pL[d][pix] = p[d];
  }
  __syncthreads();

  const float*  mrow = &mL[nc * DD];
  const double* wrow = &wL[nc * WPAD];

  float mv[DD];
  float maxAbs = 0.0f;  // fallback (li clipped to 0): max candidate == max |mv|
  #pragma unroll
  for (int d = 0; d < DD; ++d) {
    mv[d] = mrow[d] + p[d];
    maxAbs = fmaxf(maxAbs, fabsf(mv[d]));
  }

  const double t = (double)bL[nc];
  double bestA = -1.0;   // weights >= 0, so any real A >= 0
  float  bestV = 0.0f;

  // ---- pass 1: candidates v_d = +mv[d] (original indices 0..26) ----
  {
    double A[DD];
    #pragma unroll
    for (int d = 0; d < DD; ++d) A[d] = wrow[d];   // own weight (inclusive cumsum)
    #pragma unroll 1
    for (int e = 0; e < DD; ++e) {
      const float  ve  = pL[e][pix] + mrow[e];     // bit-identical to mv[e]
      const double wpe = wrow[e];
      const double wme = wrow[e + DD];
      #pragma unroll
      for (int d = 0; d < DD; ++d) {
        const float vd = mv[d];
        A[d] += (ve  > vd) ? wpe : 0.0;            // +v_e beats v_d
        A[d] += (-ve > vd) ? wme : 0.0;            // -v_e beats v_d (e==d: diag term)
      }
    }
    #pragma unroll
    for (int d = 0; d < DD; ++d) {
      const bool okc = (A[d] <= t) && (A[d] > bestA);
      bestA = okc ? A[d] : bestA;
      bestV = okc ? mv[d] : bestV;
    }
  }

  // ---- pass 2: candidates v_d = -mv[d] (original indices 27..53) ----
  {
    double A[DD];
    #pragma unroll
    for (int d = 0; d < DD; ++d) A[d] = wrow[d + DD];
    #pragma unroll 1
    for (int e = 0; e < DD; ++e) {
      const float  ve  = pL[e][pix] + mrow[e];
      const double wpe = wrow[e];
      const double wme = wrow[e + DD];
      #pragma unroll
      for (int d = 0; d < DD; ++d) {
        const float vd = -mv[d];
        A[d] += (ve  > vd) ? wpe : 0.0;            // +v_e beats -v_d (e==d: diag)
        A[d] += (-ve > vd) ? wme : 0.0;            // -v_e beats -v_d
      }
    }
    #pragma unroll
    for (int d = 0; d < DD; ++d) {
      const bool okc = (A[d] <= t) && (A[d] > bestA);
      bestA = okc ? A[d] : bestA;
      bestV = okc ? -mv[d] : bestV;
    }
  }

  const float yv = (bestA >= 0.0) ? bestV : maxAbs;
  // flat order (b, hw, nc): out[n*NCH + nc] == out[blockIdx.x*256 + tid]
  out[n * NCH + nc] = yv;
}

extern "C" void kernel_launch(void* const* d_in, const int* in_sizes, int n_in,
                              void* d_out, int out_size, void* d_ws, size_t ws_size,
                              hipStream_t stream) {
  const float* x      = (const float*)d_in[0];
  const float* mask   = (const float*)d_in[1];
  const float* weight = (const float*)d_in[2];
  const float* bias   = (const float*)d_in[3];
  float* outp = (float*)d_out;

  dim3 grid(4096);   // 65536 pixels / 16 per block
  dim3 block(256);   // 16 pixels x 16 channels
  hipLaunchKernelGGL(wos_kernel, grid, block, 0, stream, x, mask, weight, bias, outp);
}

// Round 3
// 103.219 us; speedup vs baseline: 3.2227x; 3.2227x over previous
//
#include <hip/hip_runtime.h>

// Weighted order statistic, B=4,C=3,K=3,NC=16,H=W=128, D=27, MD=54.
// One thread per (pixel, nc). Strategy: materialize the 54 candidates
// (+/-(mask+patch)) with their weights, sort descending with a fully
// unrolled 64-wide bitonic network (10 sentinels -inf / weight 0), then
// inclusive f32 cumsum in sorted order (bit-identical to the reference's
// jnp.cumsum) and pick the value at the last position with accw <= bias.
// Fallback (li clipped to 0) = sorted max = v[0].
// Output layout: reference reshapes (b*hw, NC) -> (b, NC, h, w) without
// transpose, so flat order is (b, hw, nc) -> out[n*NCH + nc].

#define NCH 16
#define DD  27
#define MDD 54
#define HH  128
#define WW  128
#define CCH 3

__global__ __launch_bounds__(256) void wos_kernel(
    const float* __restrict__ xin,
    const float* __restrict__ mask,
    const float* __restrict__ weight,
    const float* __restrict__ bias,
    float* __restrict__ out)
{
  __shared__ float mL[NCH * DD];
  __shared__ float wS[NCH * MDD];
  __shared__ float bL[NCH];

  const int tid = threadIdx.x;
  for (int i = tid; i < NCH * DD; i += 256) mL[i] = mask[i];
  for (int i = tid; i < NCH * MDD; i += 256) wS[i] = weight[i];
  if (tid < NCH) bL[tid] = bias[tid];

  const int nc  = tid & 15;
  const int pix = tid >> 4;
  const int n   = (int)blockIdx.x * 16 + pix;   // grid covers B*H*W = 65536
  const int b   = n >> 14;                      // H*W = 16384
  const int rem = n & 16383;
  const int py  = rem >> 7;
  const int px  = rem & 127;

  // 3x3x3 patch with 'same' zero padding (d = c*9 + i*3 + j)
  float p[DD];
  #pragma unroll
  for (int c = 0; c < CCH; ++c) {
    #pragma unroll
    for (int i = 0; i < 3; ++i) {
      const int ys = py + i - 1;
      const bool yok = (ys >= 0) && (ys < HH);
      #pragma unroll
      for (int j = 0; j < 3; ++j) {
        const int xs = px + j - 1;
        const bool ok = yok && (xs >= 0) && (xs < WW);
        const int idx = ((b * CCH + c) * HH + (ok ? ys : 0)) * WW + (ok ? xs : 0);
        p[c * 9 + i * 3 + j] = ok ? xin[idx] : 0.0f;
      }
    }
  }

  __syncthreads();

  const float* mrow = &mL[nc * DD];
  const float* wrow = &wS[nc * MDD];
  const float  t    = bL[nc];

  // candidates + payload weights
  float v[64], w[64];
  #pragma unroll
  for (int d = 0; d < DD; ++d) {
    const float m = mrow[d] + p[d];
    v[d]      = m;
    v[DD + d] = -m;
    w[d]      = wrow[d];
    w[DD + d] = wrow[DD + d];
  }
  #pragma unroll
  for (int i = MDD; i < 64; ++i) {
    v[i] = -__builtin_inff();   // sinks to positions 54..63
    w[i] = 0.0f;
  }

  // bitonic sort, descending, fully unrolled (static register indexing)
  #pragma unroll
  for (int k = 2; k <= 64; k <<= 1) {
    #pragma unroll
    for (int j = k >> 1; j > 0; j >>= 1) {
      #pragma unroll
      for (int i = 0; i < 64; ++i) {
        const int l = i ^ j;
        if (l > i) {
          const bool up = ((i & k) == 0);     // descending blocks
          const float vi = v[i], vl = v[l];
          const float wi = w[i], wl = w[l];
          const bool sw = up ? (vi < vl) : (vi > vl);
          v[i] = sw ? vl : vi;
          v[l] = sw ? vi : vl;
          w[i] = sw ? wl : wi;
          w[l] = sw ? wi : wl;
        }
      }
    }
  }

  // inclusive cumsum in sorted order (same f32 add sequence as reference),
  // select value at last position with accw <= t; fallback = v[0] (li->0).
  float acc = 0.0f;
  float y   = v[0];
  #pragma unroll
  for (int i = 0; i < MDD; ++i) {
    acc += w[i];
    y = (acc <= t) ? v[i] : y;
  }

  // flat order (b, hw, nc): out[n*NCH + nc] == out[blockIdx.x*256 + tid]
  out[n * NCH + nc] = y;
}

extern "C" void kernel_launch(void* const* d_in, const int* in_sizes, int n_in,
                              void* d_out, int out_size, void* d_ws, size_t ws_size,
                              hipStream_t stream) {
  const float* x      = (const float*)d_in[0];
  const float* mask   = (const float*)d_in[1];
  const float* weight = (const float*)d_in[2];
  const float* bias   = (const float*)d_in[3];
  float* outp = (float*)d_out;

  dim3 grid(4096);   // 65536 pixels / 16 per block
  dim3 block(256);   // 16 pixels x 16 channels
  hipLaunchKernelGGL(wos_kernel, grid, block, 0, stream, x, mask, weight, bias, outp);
}

// Round 5
// 67.854 us; speedup vs baseline: 4.9025x; 1.5212x over previous
//
#include <hip/hip_runtime.h>

// Weighted order statistic, B=4,C=3,K=3,NC=16,H=W=128, D=27, MD=54.
// One thread per (pixel, nc). The 54 candidates are +/-m of 27 values
// m_d = mask[nc,d] + patch[d]. Exploit that:
//   1) sort the 27 m's ONCE, descending, as exact 32-bit monotone keys
//      (f2key) with a u32 index payload — 32-wide bitonic network, 240 CEs;
//   2) the -m list is free: f2key(-v) = ~f2key(v); slots 32..63 = ~key[i]
//      (ascending) with payload idx+27 -> canonical bitonic (desc++asc);
//   3) one 64-wide bitonic merge (192 CEs, all-descending compare-exchanges);
//   4) static walk over merged positions 5..58 (five 0xFFFFFFFF sentinel
//      complements deterministically at 0..4, five zero-keys at 59..63):
//      f32 inclusive cumsum of weights in EXACT sorted order (bit-identical
//      to the reference's cumsum), select last position with acc <= bias,
//      fallback = position 5 (the max candidate, li clipped to 0).
// Keys are full 32 bits -> ordering exact, value reconstruction exact.
// Output layout: reference reshapes (b*hw, NC) -> (b,NC,h,w) without
// transpose, so flat order is (b, hw, nc) -> out[n*NCH + nc].

#define NCH 16
#define DD  27
#define MDD 54
#define HH  128
#define WW  128
#define CCH 3

__device__ __forceinline__ unsigned f2key(unsigned bits) {
  // monotone: ascending uint order == ascending float order (no NaN inputs)
  const unsigned s = (unsigned)((int)bits >> 31);
  return bits ^ (s | 0x80000000u);
}

__global__ __launch_bounds__(256, 2) void wos_kernel(
    const float* __restrict__ xin,
    const float* __restrict__ mask,
    const float* __restrict__ weight,
    const float* __restrict__ bias,
    float* __restrict__ out)
{
  __shared__ float mL[NCH * DD];
  __shared__ float wS[NCH * MDD];
  __shared__ float bL[NCH];

  const int tid = threadIdx.x;
  for (int i = tid; i < NCH * DD; i += 256) mL[i] = mask[i];
  for (int i = tid; i < NCH * MDD; i += 256) wS[i] = weight[i];
  if (tid < NCH) bL[tid] = bias[tid];

  const int nc  = tid & 15;
  const int pix = tid >> 4;
  const int n   = (int)blockIdx.x * 16 + pix;   // grid covers B*H*W = 65536
  const int b   = n >> 14;                      // H*W = 16384
  const int rem = n & 16383;
  const int py  = rem >> 7;
  const int px  = rem & 127;

  // 3x3x3 patch with 'same' zero padding (d = c*9 + i*3 + j)
  float p[DD];
  #pragma unroll
  for (int c = 0; c < CCH; ++c) {
    #pragma unroll
    for (int i = 0; i < 3; ++i) {
      const int ys = py + i - 1;
      const bool yok = (ys >= 0) && (ys < HH);
      #pragma unroll
      for (int j = 0; j < 3; ++j) {
        const int xs = px + j - 1;
        const bool ok = yok && (xs >= 0) && (xs < WW);
        const int idx = ((b * CCH + c) * HH + (ok ? ys : 0)) * WW + (ok ? xs : 0);
        p[c * 9 + i * 3 + j] = ok ? xin[idx] : 0.0f;
      }
    }
  }

  __syncthreads();

  const float* mrow = &mL[nc * DD];
  const float  t    = bL[nc];

  unsigned key[64], pay[64];
  #pragma unroll
  for (int d = 0; d < DD; ++d) {
    const float m = mrow[d] + p[d];
    key[d] = f2key(__float_as_uint(m));   // full 32-bit exact key
    pay[d] = (unsigned)d;                 // weight index for +m_d
  }
  #pragma unroll
  for (int i = DD; i < 32; ++i) { key[i] = 0u; pay[i] = 0u; }  // low sentinels

  // bitonic sort of slots 0..31, descending (payload follows key)
  #pragma unroll
  for (int k = 2; k <= 32; k <<= 1) {
    #pragma unroll
    for (int j = k >> 1; j > 0; j >>= 1) {
      #pragma unroll
      for (int i = 0; i < 32; ++i) {
        const int l = i ^ j;
        if (l > i) {
          const bool up = ((i & k) == 0);          // up -> descending block
          const unsigned ka = key[i], kb = key[l];
          const unsigned pa = pay[i], pb = pay[l];
          const bool sw = up ? (ka < kb) : (ka > kb);
          key[i] = sw ? kb : ka;  key[l] = sw ? ka : kb;
          pay[i] = sw ? pb : pa;  pay[l] = sw ? pa : pb;
        }
      }
    }
  }

  // slots 32..63: the -m list, ascending: f2key(-v) = ~f2key(v).
  // (sentinel complements 0xFFFFFFFF end up at ascending top -> merged 0..4)
  #pragma unroll
  for (int i = 0; i < 32; ++i) {
    key[32 + i] = ~key[i];
    pay[32 + i] = pay[i] + DD;      // weight index for -m_d
  }

  // bitonic merge of 64 (input: 0..31 descending, 32..63 ascending),
  // all CEs descending (identical to the k=64 stage of a full bitonic sort)
  #pragma unroll
  for (int j = 32; j > 0; j >>= 1) {
    #pragma unroll
    for (int i = 0; i < 64; ++i) {
      const int l = i ^ j;
      if (l > i) {
        const unsigned ka = key[i], kb = key[l];
        const unsigned pa = pay[i], pb = pay[l];
        const bool sw = (ka < kb);
        key[i] = sw ? kb : ka;  key[l] = sw ? ka : kb;
        pay[i] = sw ? pb : pa;  pay[l] = sw ? pa : pb;
      }
    }
  }

  // walk real positions 5..58: inclusive f32 cumsum of weights in exact
  // sorted order; select last position with acc <= t; fallback = pos 5.
  const int wbase = nc * MDD;
  float acc = 0.0f;
  unsigned ykey = key[5];
  #pragma unroll
  for (int pos = 5; pos < 59; ++pos) {
    const float w = wS[wbase + (int)pay[pos]];
    acc += w;
    ykey = (acc <= t) ? key[pos] : ykey;
  }

  // exact inverse of f2key
  const unsigned bits = (ykey & 0x80000000u) ? (ykey ^ 0x80000000u) : ~ykey;
  const float y = __uint_as_float(bits);

  // flat order (b, hw, nc): out[n*NCH + nc] == out[blockIdx.x*256 + tid]
  out[n * NCH + nc] = y;
}

extern "C" void kernel_launch(void* const* d_in, const int* in_sizes, int n_in,
                              void* d_out, int out_size, void* d_ws, size_t ws_size,
                              hipStream_t stream) {
  const float* x      = (const float*)d_in[0];
  const float* mask   = (const float*)d_in[1];
  const float* weight = (const float*)d_in[2];
  const float* bias   = (const float*)d_in[3];
  float* outp = (float*)d_out;

  dim3 grid(4096);   // 65536 pixels / 16 per block
  dim3 block(256);   // 16 pixels x 16 channels
  hipLaunchKernelGGL(wos_kernel, grid, block, 0, stream, x, mask, weight, bias, outp);
}

// Round 6
// 63.143 us; speedup vs baseline: 5.2682x; 1.0746x over previous
//
#include <hip/hip_runtime.h>

// Weighted order statistic, B=4,C=3,K=3,NC=16,H=W=128, D=27, MD=54.
// One thread per (pixel, nc). Pipeline:
//   1) cooperative LDS staging of the 16 pixels' 3x3x3 patches;
//   2) 27 keys = f2key(mask+patch) (exact 32-bit monotone map) + index payload;
//   3) Batcher merge-exchange sort of 32 slots (27 real + 5 zero sentinels),
//      DESCENDING — 191 CEs, sentinel CEs constant-fold;
//   4) sign-split (the j=32 bitonic-merge stage done as a sign test):
//      top[i] = max(key,~key) (= |m| side), bottom[i] = ~top[i];
//      payloads: tp = neg ? d+27 : d, bp = (2d+27) - tp;
//      top is bitonic with five 0xFFFFFFFF sentinels -> sorted positions 0..4,
//      bottom bitonic with five 0 sentinels -> positions 27..31 of its half;
//   5) two 32-wide bitonic merges, descending (80 CEs each);
//   6) walk global positions 5..58 (top 5..31, then bottom 0..26): inclusive
//      f32 cumsum of weights (LDS gather by original index) in EXACT sorted
//      order — bit-identical add sequence to the reference's jnp.cumsum —
//      select last position with acc <= bias; fallback = position 5 (max).
// Output layout: reference reshapes (b*hw, NC) -> (b,NC,h,w) without
// transpose, so flat order is (b, hw, nc) -> out[n*NCH + nc].

#define NCH 16
#define DD  27
#define MDD 54
#define HH  128
#define WW  128
#define CCH 3

__device__ __forceinline__ unsigned f2key(unsigned bits) {
  // monotone: ascending uint order == ascending float order (no NaN inputs)
  const unsigned s = (unsigned)((int)bits >> 31);
  return bits ^ (s | 0x80000000u);
}

__global__ __launch_bounds__(256, 2) void wos_kernel(
    const float* __restrict__ xin,
    const float* __restrict__ mask,
    const float* __restrict__ weight,
    const float* __restrict__ bias,
    float* __restrict__ out)
{
  __shared__ float mL[NCH][28];     // mask rows, padded stride (f2-aligned)
  __shared__ float wS[NCH * MDD];   // weights (walk gather)
  __shared__ float bL[NCH];
  __shared__ float pL[16][28];      // per-pixel patches, padded stride

  const int tid = threadIdx.x;
  for (int i = tid; i < NCH * DD; i += 256) mL[i / DD][i % DD] = mask[i];
  for (int i = tid; i < NCH * MDD; i += 256) wS[i] = weight[i];
  if (tid < NCH) bL[tid] = bias[tid];

  const int nc   = tid & 15;
  const int pix  = tid >> 4;
  const int base = (int)blockIdx.x * 16;   // 16 pixels per block

  // cooperative patch staging: 16 pixels x 27 taps, 'same' zero padding
  for (int i = tid; i < 16 * DD; i += 256) {
    const int pp = i / DD;
    const int d  = i - pp * DD;
    const int nn = base + pp;
    const int bb = nn >> 14;            // H*W = 16384
    const int rr = nn & 16383;
    const int yy = rr >> 7;
    const int xx = rr & 127;
    const int c  = d / 9;
    const int ij = d - c * 9;
    const int di = ij / 3;
    const int dj = ij - di * 3;
    const int ys = yy + di - 1;
    const int xs = xx + dj - 1;
    const bool ok = ((unsigned)ys < (unsigned)HH) && ((unsigned)xs < (unsigned)WW);
    pL[pp][d] = ok ? xin[((bb * CCH + c) * HH + ys) * WW + xs] : 0.0f;
  }
  __syncthreads();

  const float t = bL[nc];

  // build 27 exact keys + index payloads (float2-paired LDS reads)
  unsigned key[32], pay[32];
  {
    float m[DD];
    #pragma unroll
    for (int q = 0; q < 13; ++q) {
      const float2 mk = *reinterpret_cast<const float2*>(&mL[nc][2 * q]);
      const float2 pc = *reinterpret_cast<const float2*>(&pL[pix][2 * q]);
      m[2 * q]     = mk.x + pc.x;
      m[2 * q + 1] = mk.y + pc.y;
    }
    m[26] = mL[nc][26] + pL[pix][26];
    #pragma unroll
    for (int d = 0; d < DD; ++d) {
      key[d] = f2key(__float_as_uint(m[d]));
      pay[d] = (unsigned)d;
    }
  }
  #pragma unroll
  for (int i = DD; i < 32; ++i) { key[i] = 0u; pay[i] = 0u; }  // low sentinels

  // Batcher merge-exchange sort (Knuth 5.2.2M, n=32), DESCENDING.
  // Passes (p,d,r): CE(i,i+d) for i < 32-d with (i & p) == r. 191 CEs.
  {
    constexpr int P_[15][3] = {
      {16,16,0},{8,8,0},{8,8,8},{4,4,0},{4,12,4},{4,4,4},
      {2,2,0},{2,14,2},{2,6,2},{2,2,2},
      {1,1,0},{1,15,1},{1,7,1},{1,3,1},{1,1,1}};
    #pragma unroll
    for (int s = 0; s < 15; ++s) {
      const int p = P_[s][0], d = P_[s][1], r = P_[s][2];
      #pragma unroll
      for (int i = 0; i < 32 - d; ++i) {
        if ((i & p) == r) {
          const int l = i + d;
          const unsigned ka = key[i], kb = key[l];
          const unsigned pa = pay[i], pb = pay[l];
          const bool sw = (ka < kb);            // descending: max at i
          key[i] = sw ? kb : ka;  key[l] = sw ? ka : kb;
          pay[i] = sw ? pb : pa;  pay[l] = sw ? pa : pb;
        }
      }
    }
  }

  // sign-split: top = larger of (+m, -m) per slot, bottom = complement.
  unsigned tk[32], tp[32], bk[32], bp[32];
  #pragma unroll
  for (int i = 0; i < 32; ++i) {
    const bool neg = key[i] < 0x80000000u;      // m < 0 (sentinels: true)
    tk[i] = neg ? ~key[i] : key[i];
    bk[i] = ~tk[i];
    tp[i] = neg ? pay[i] + DD : pay[i];
    bp[i] = (pay[i] * 2u + DD) - tp[i];         // the other index of the pair
  }

  const int wbase = nc * MDD;
  float acc = 0.0f;
  unsigned ykey;

  // top half: bitonic merge of 32, descending, then walk positions 5..31
  {
    #pragma unroll
    for (int j = 16; j >= 1; j >>= 1) {
      #pragma unroll
      for (int i = 0; i < 32; ++i) {
        if ((i & j) == 0) {
          const int l = i + j;
          const unsigned ka = tk[i], kb = tk[l];
          const unsigned pa = tp[i], pb = tp[l];
          const bool sw = (ka < kb);
          tk[i] = sw ? kb : ka;  tk[l] = sw ? ka : kb;
          tp[i] = sw ? pb : pa;  tp[l] = sw ? pa : pb;
        }
      }
    }
    ykey = tk[5];                      // max real candidate (li clipped to 0)
    #pragma unroll
    for (int pos = 5; pos < 32; ++pos) {
      acc += wS[wbase + (int)tp[pos]];
      ykey = (acc <= t) ? tk[pos] : ykey;
    }
  }

  // bottom half: bitonic merge of 32, descending, then walk positions 0..26
  {
    #pragma unroll
    for (int j = 16; j >= 1; j >>= 1) {
      #pragma unroll
      for (int i = 0; i < 32; ++i) {
        if ((i & j) == 0) {
          const int l = i + j;
          const unsigned ka = bk[i], kb = bk[l];
          const unsigned pa = bp[i], pb = bp[l];
          const bool sw = (ka < kb);
          bk[i] = sw ? kb : ka;  bk[l] = sw ? ka : kb;
          bp[i] = sw ? pb : pa;  bp[l] = sw ? pa : pb;
        }
      }
    }
    #pragma unroll
    for (int pos = 0; pos < DD; ++pos) {
      acc += wS[wbase + (int)bp[pos]];
      ykey = (acc <= t) ? bk[pos] : ykey;
    }
  }

  // exact inverse of f2key
  const unsigned bits = (ykey & 0x80000000u) ? (ykey ^ 0x80000000u) : ~ykey;
  // flat order (b, hw, nc)
  out[(base + pix) * NCH + nc] = __uint_as_float(bits);
}

extern "C" void kernel_launch(void* const* d_in, const int* in_sizes, int n_in,
                              void* d_out, int out_size, void* d_ws, size_t ws_size,
                              hipStream_t stream) {
  const float* x      = (const float*)d_in[0];
  const float* mask   = (const float*)d_in[1];
  const float* weight = (const float*)d_in[2];
  const float* bias   = (const float*)d_in[3];
  float* outp = (float*)d_out;

  dim3 grid(4096);   // 65536 pixels / 16 per block
  dim3 block(256);   // 16 pixels x 16 channels
  hipLaunchKernelGGL(wos_kernel, grid, block, 0, stream, x, mask, weight, bias, outp);
}